// Round 7
// baseline (4640.377 us; speedup 1.0000x reference)
//
#include <hip/hip_runtime.h>
#include <math.h>

#define B_  32
#define T_  64
#define TW_ 32
#define EW_ 300
#define H_  512
#define E_  1024
#define HH_ 512
#define C_  7
#define N_  2048   // B*T

typedef float f32x4 __attribute__((ext_vector_type(4)));
typedef short s16x8 __attribute__((ext_vector_type(8)));
typedef unsigned short u16;
typedef unsigned int u32;

__device__ __forceinline__ float sigm(float x){ return 1.f/(1.f+expf(-x)); }
__device__ __forceinline__ float bf2f(u16 u){
  union{float f; unsigned v;} x; x.v = ((unsigned)u)<<16; return x.f;
}
__device__ __forceinline__ u16 f2bf(float f){
  union{float f; unsigned v;} x; x.f = f;
  unsigned r = x.v + 0x7FFF + ((x.v>>16)&1);
  return (u16)(r>>16);
}
// async 16B global->LDS (dest: wave-uniform base + lane*16)
__device__ __forceinline__ void g2lds16(const void* g, void* l){
  __builtin_amdgcn_global_load_lds((const __attribute__((address_space(1))) u32*)g,
                                   (__attribute__((address_space(3))) u32*)l, 16, 0, 0);
}

// ===========================================================================
// Pre-pass packing kernels (verified R6)
// ===========================================================================
__global__ __launch_bounds__(256) void k_pack_w(
    const float* __restrict__ Wih_f, const float* __restrict__ Whh_f,
    const float* __restrict__ Wih_b, const float* __restrict__ Whh_b,
    u16* __restrict__ Wpk)
{
  size_t idx = (size_t)blockIdx.x*256 + threadIdx.x;
  if(idx >= (size_t)32*26*4096) return;
  int c   = (int)(idx & 31);
  int row = (int)((idx >> 5) & 127);
  int kc  = (int)((idx >> 12) % 26);
  int pan = (int)(idx / ((size_t)26*4096));
  int dir = pan >> 4, mt = pan & 15;
  int g = row >> 5, ml = row & 31;
  int R = g*512 + mt*32 + ml;
  int k = kc*32 + c;
  const float* Wih = dir ? Wih_b : Wih_f;
  const float* Whh = dir ? Whh_b : Whh_f;
  float v = (k < 320) ? ((k < EW_) ? Wih[(size_t)R*EW_ + k] : 0.f)
                      : Whh[(size_t)R*H_ + (k-320)];
  Wpk[idx] = f2bf(v);
}

__global__ __launch_bounds__(256) void k_pack_x(
    const float* __restrict__ input, u16* __restrict__ xpk)
{
  size_t idx = (size_t)blockIdx.x*256 + threadIdx.x;
  if(idx >= (size_t)32*16*10*4096) return;
  int c   = (int)(idx & 31);
  int row = (int)((idx >> 5) & 127);
  int kc  = (int)((idx >> 12) % 10);
  int q2  = (int)((idx >> 12) / 10);      // wt*16+nt
  int nt  = q2 & 15, wt = q2 >> 4;
  int n = nt*128 + row;
  int k = kc*32 + c;
  float v = (k < EW_) ? input[((size_t)n*TW_ + wt)*EW_ + k] : 0.f;
  xpk[idx] = f2bf(v);
}

__global__ __launch_bounds__(256) void k_f2bf(const float* __restrict__ src,
                                              u16* __restrict__ dst, int n)
{
  int idx = blockIdx.x*256 + threadIdx.x;
  if(idx < n) dst[idx] = f2bf(src[idx]);
}

__global__ __launch_bounds__(256) void k_wattT(const float* __restrict__ W,
                                               u16* __restrict__ dst)
{
  int idx = blockIdx.x*256 + threadIdx.x;
  if(idx >= E_*E_) return;
  int j = idx >> 10, k = idx & 1023;
  dst[idx] = f2bf(W[(size_t)k*E_ + j]);   // dst[j][k] = W[k][j]
}

// ===========================================================================
// Phase 1: PERSISTENT BiLSTM. One launch, 512 blocks (=2/CU, co-resident via
// __launch_bounds__(256,2)), 32 internal time steps. c in REGISTERS.
// Block bx: group g = bx&31 (dir=g&1, nt=g>>1), member mt = bx>>5 — group
// members differ by 32 in id (same XCD under round-robin; correctness does
// NOT depend on it: device-scope atomics+fences). One group barrier (16
// blocks) per step; next step's x-chunks prefetched under the spin.
// ===========================================================================
__global__ __launch_bounds__(256, 2) void lstm_p(
    const u16* __restrict__ xpk, const u16* __restrict__ Wpk,
    const float* __restrict__ b_f, const float* __restrict__ b_b,
    u16* __restrict__ hpkA, u16* __restrict__ hpkB,
    u16* __restrict__ featsbf, u32* __restrict__ bar)
{
  const int bx = blockIdx.x;
  const int g  = bx & 31, mt = bx >> 5;
  const int dir = g & 1, nt = g >> 1;
  const u16* srcW = Wpk + (size_t)(dir*16+mt)*26*4096;

  __shared__ __align__(16) u16 As[3][4096];
  __shared__ __align__(16) u16 Bs[3][4096];

  const int tid = threadIdx.x;
  const int w = tid >> 6, l = tid & 63;
  const int lr = l & 15, lh = l >> 4;
  const int wn = w >> 1, wm = w & 1;

  const float* bias = dir ? b_b : b_f;
  const int col = wm*16 + lr;
  const int m = mt*32 + col;
  const float bi = bias[m], bfv = bias[H_+m], bg = bias[2*H_+m], bo = bias[3*H_+m];

  float creg[4][4];
  #pragma unroll
  for(int a=0;a<4;a++){ creg[a][0]=0.f; creg[a][1]=0.f; creg[a][2]=0.f; creg[a][3]=0.f; }

  auto stage = [&](const u16* sX, const u16* sH, int kc, int b){
    const u16* aB = (kc < 10) ? (sX + (size_t)kc*4096) : (sH + (size_t)(kc-10)*4096);
    const u16* bB = srcW + (size_t)kc*4096;
    #pragma unroll
    for(int c=0;c<2;++c){
      const int cc = w*2 + c;
      g2lds16((const char*)aB + cc*1024 + l*16, (char*)&As[b][0] + cc*1024);
      g2lds16((const char*)bB + cc*1024 + l*16, (char*)&Bs[b][0] + cc*1024);
    }
  };

  // prologue: t=0 chunks 0,1 (x chunks)
  {
    const int wt0 = dir ? (TW_-1) : 0;
    const u16* sX0 = xpk + (size_t)(wt0*16+nt)*10*4096;
    stage(sX0, nullptr, 0, 0);
    stage(sX0, nullptr, 1, 1);
  }

  #pragma unroll 1
  for(int t=0; t<TW_; ++t){
    const int wt = dir ? (TW_-1-t) : t;
    const u16* sX = xpk + (size_t)(wt*16+nt)*10*4096;
    const u16* hin  = (t & 1) ? hpkB : hpkA;
    u16*       hout = (t & 1) ? hpkA : hpkB;
    const u16* sH = hin + (size_t)(dir*16+nt)*16*4096;

    f32x4 acc[4][4];
    #pragma unroll
    for(int a=0;a<4;a++)
      #pragma unroll
      for(int gg=0;gg<4;gg++) acc[a][gg] = (f32x4){0.f,0.f,0.f,0.f};

    #pragma unroll
    for(int kc=0; kc<26; ++kc){
      if(kc < 25) asm volatile("s_waitcnt vmcnt(4)" ::: "memory");
      else        asm volatile("s_waitcnt vmcnt(0)" ::: "memory");
      __builtin_amdgcn_s_barrier();
      __builtin_amdgcn_sched_barrier(0);
      if(kc+2 < 26) stage(sX, sH, kc+2, (kc+2)%3);
      const int cu = kc % 3;
      s16x8 av[4], bv[4];
      #pragma unroll
      for(int nf=0; nf<4; ++nf)
        av[nf] = *(const s16x8*)&As[cu][(wn*64 + nf*16 + lr)*32 + lh*8];
      #pragma unroll
      for(int gg=0; gg<4; ++gg)
        bv[gg] = *(const s16x8*)&Bs[cu][(gg*32 + wm*16 + lr)*32 + lh*8];
      #pragma unroll
      for(int gg=0; gg<4; ++gg)
        #pragma unroll
        for(int nf=0; nf<4; ++nf)
          acc[nf][gg] = __builtin_amdgcn_mfma_f32_16x16x32_bf16(av[nf], bv[gg], acc[nf][gg], 0,0,0);
    }
    // all waves done reading LDS buffers
    __builtin_amdgcn_s_barrier();

    // cell update (c in regs) + h/feats write
    u16* hop = hout + ((size_t)(dir*16+nt)*16 + mt)*4096;
    const int n0 = nt*128;
    #pragma unroll
    for(int nf=0; nf<4; ++nf){
      #pragma unroll
      for(int r=0; r<4; ++r){
        const int row = wn*64 + nf*16 + lh*4 + r;
        float gi = acc[nf][0][r] + bi;
        float gf = acc[nf][1][r] + bfv;
        float gc = acc[nf][2][r] + bg;
        float go = acc[nf][3][r] + bo;
        float c2 = sigm(gf)*creg[nf][r] + sigm(gi)*tanhf(gc);
        float h2 = sigm(go)*tanhf(c2);
        creg[nf][r] = c2;
        if(t == TW_-1) featsbf[(size_t)(n0+row)*E_ + dir*H_ + m] = f2bf(h2);
        else           hop[row*32 + col] = f2bf(h2);
      }
    }

    if(t < TW_-1){
      __threadfence();                                   // h stores visible (device scope)
      if(tid == 0)
        __hip_atomic_fetch_add(&bar[g], 1u, __ATOMIC_RELEASE, __HIP_MEMORY_SCOPE_AGENT);
      // prefetch next step's x chunks 0,1 under the barrier spin (read-only src)
      {
        const int wt2 = dir ? (TW_-1-(t+1)) : (t+1);
        const u16* sX2 = xpk + (size_t)(wt2*16+nt)*10*4096;
        stage(sX2, nullptr, 0, 0);
        stage(sX2, nullptr, 1, 1);
      }
      if(tid == 0){
        const u32 want = (u32)(16*(t+1));
        while(__hip_atomic_load(&bar[g], __ATOMIC_ACQUIRE, __HIP_MEMORY_SCOPE_AGENT) < want)
          __builtin_amdgcn_s_sleep(2);
      }
      __syncthreads();
    }
  }
}

// ===========================================================================
// q = feats @ W_att  (one-time, bf16 MFMA, fp32 out)  [verified]
// ===========================================================================
__global__ __launch_bounds__(256) void k_qgemm(const u16* __restrict__ featsbf,
                                               const u16* __restrict__ WattT,
                                               float* __restrict__ q)
{
  const int n0 = blockIdx.x*64, j0 = blockIdx.y*64;
  __shared__ __align__(16) u16 As[64*40];
  __shared__ __align__(16) u16 Bs[64*40];
  const int tid = threadIdx.x;
  const int w = tid>>6, l = tid&63, lr = l&15, lk = (l>>4)*8;
  const int arow = tid>>2, ak8 = (tid&3)*8;

  f32x4 acc[4];
  #pragma unroll
  for(int i=0;i<4;i++) acc[i] = (f32x4){0.f,0.f,0.f,0.f};

  for(int kc=0; kc<32; ++kc){
    *(s16x8*)&As[arow*40 + ak8] = *(const s16x8*)&featsbf[(size_t)(n0+arow)*E_ + kc*32 + ak8];
    *(s16x8*)&Bs[arow*40 + ak8] = *(const s16x8*)&WattT[(size_t)(j0+arow)*E_ + kc*32 + ak8];
    __syncthreads();
    s16x8 av = *(const s16x8*)&As[(w*16 + lr)*40 + lk];
    #pragma unroll
    for(int mf=0; mf<4; ++mf){
      s16x8 bv = *(const s16x8*)&Bs[(mf*16 + lr)*40 + lk];
      acc[mf] = __builtin_amdgcn_mfma_f32_16x16x32_bf16(av, bv, acc[mf], 0,0,0);
    }
    __syncthreads();
  }
  #pragma unroll
  for(int mf=0; mf<4; ++mf)
    #pragma unroll
    for(int r=0; r<4; ++r){
      int n = n0 + w*16 + (l>>4)*4 + r;
      q[(size_t)n*E_ + j0 + mf*16 + lr] = acc[mf][r];
    }
}

// ===========================================================================
// Phase 2 building blocks  [unchanged - verified correct R4-R6]
// ===========================================================================
struct GArg2 {
  const u16* xA; const u16* xB;
  long ldA; long ldB;
  const u16* W; int K;
};

__device__ __forceinline__ void gemm32v2(const GArg2 a, int R, int xt, int ks,
                                         int KS, int z, float* __restrict__ part,
                                         char* smem)
{
  u16* Xs0 = (u16*)smem;
  u16* Xs1 = Xs0 + 32*40;
  u16* Ws0 = Xs1 + 32*40;
  u16* Ws1 = Ws0 + 128*32;
  const int Kc = a.K / KS;
  const int nch = Kc >> 5;
  const int kb0 = ks * Kc;
  const int tid = threadIdx.x;
  const int w = tid>>6, l = tid&63, lr = l&15, lh = l>>4;

  f32x4 a00={0,0,0,0}, a01={0,0,0,0}, a10={0,0,0,0}, a11={0,0,0,0};

  auto issueW = [&](int c, u16* Wb){
    const int kb = kb0 + c*32;
    #pragma unroll
    for(int c2=0;c2<2;++c2){
      const int cc = w*2 + c2;
      const char* g = (const char*)(a.W + (size_t)(xt*128 + cc*16 + (l>>2))*a.K + kb) + (l&3)*16;
      g2lds16(g, (char*)Wb + cc*1024);
    }
  };
  auto loadX = [&](int c, short4* xr){
    const int kb = kb0 + c*32;
    const int row = tid>>3, k4 = (tid&7)*4;
    short4 xv = *(const short4*)&a.xA[(size_t)row*a.ldA + kb + k4];
    if(a.xB){
      short4 yv = *(const short4*)&a.xB[(size_t)row*a.ldB + kb + k4];
      xv.x = (short)f2bf(bf2f((u16)xv.x)+bf2f((u16)yv.x));
      xv.y = (short)f2bf(bf2f((u16)xv.y)+bf2f((u16)yv.y));
      xv.z = (short)f2bf(bf2f((u16)xv.z)+bf2f((u16)yv.z));
      xv.w = (short)f2bf(bf2f((u16)xv.w)+bf2f((u16)yv.w));
    }
    *xr = xv;
  };
  auto writeX = [&](short4 xv, u16* Xb){
    *(short4*)&Xb[(tid>>3)*40 + (tid&7)*4] = xv;
  };

  short4 xr;
  issueW(0, Ws0); loadX(0, &xr); writeX(xr, Xs0);
  __syncthreads();
  for(int c=0;c<nch;++c){
    u16* Xc = (c&1)?Xs1:Xs0; u16* Wc = (c&1)?Ws1:Ws0;
    u16* Xn = (c&1)?Xs0:Xs1; u16* Wn = (c&1)?Ws0:Ws1;
    const bool pre = (c+1 < nch);
    if(pre){ issueW(c+1, Wn); loadX(c+1, &xr); }
    s16x8 av0 = *(const s16x8*)&Xc[lr*40 + lh*8];
    s16x8 av1 = *(const s16x8*)&Xc[(16+lr)*40 + lh*8];
    s16x8 bv0 = *(const s16x8*)&Wc[(w*32 + lr)*32 + lh*8];
    s16x8 bv1 = *(const s16x8*)&Wc[(w*32 + 16 + lr)*32 + lh*8];
    a00 = __builtin_amdgcn_mfma_f32_16x16x32_bf16(av0, bv0, a00, 0,0,0);
    a01 = __builtin_amdgcn_mfma_f32_16x16x32_bf16(av0, bv1, a01, 0,0,0);
    a10 = __builtin_amdgcn_mfma_f32_16x16x32_bf16(av1, bv0, a10, 0,0,0);
    a11 = __builtin_amdgcn_mfma_f32_16x16x32_bf16(av1, bv1, a11, 0,0,0);
    if(pre) writeX(xr, Xn);
    __syncthreads();
  }
  float* dst = part + (size_t)((z*KS + ks)*B_)*R + xt*128 + w*32;
  f32x4 accs[2][2] = {{a00,a01},{a10,a11}};
  #pragma unroll
  for(int nf=0; nf<2; ++nf)
    #pragma unroll
    for(int mf=0; mf<2; ++mf)
      #pragma unroll
      for(int r=0; r<4; ++r){
        int n = nf*16 + lh*4 + r;
        dst[(size_t)n*R + mf*16 + lr] = accs[nf][mf][r];
      }
}

__device__ __forceinline__ void att_body(const float* __restrict__ q,
                                         const u16* __restrict__ histbf,
                                         const u16* __restrict__ featsbf,
                                         u16* __restrict__ xcbf,
                                         int i, int b, char* smem)
{
  float* qs = (float*)smem;      // 1024
  float* sc = qs + E_;           // 64
  const int tid = threadIdx.x;
  *(float4*)&qs[tid*4] = *(const float4*)&q[((size_t)b*T_ + i)*E_ + tid*4];
  __syncthreads();
  const int wv = tid>>6, ln = tid&63;
  for(int L = wv; L <= i; L += 4){
    const u16* hl = histbf + ((size_t)L*B_ + b)*E_;
    float s = 0.f;
    s16x8 h0 = *(const s16x8*)&hl[ln*16];
    s16x8 h1 = *(const s16x8*)&hl[ln*16 + 8];
    #pragma unroll
    for(int j=0;j<8;j++){
      s += qs[ln*16 + j]     * bf2f((u16)h0[j]);
      s += qs[ln*16 + 8 + j] * bf2f((u16)h1[j]);
    }
    #pragma unroll
    for(int off=32; off; off>>=1) s += __shfl_down(s, off);
    if(ln == 0) sc[L] = s;
  }
  __syncthreads();
  if(tid < 64){
    float v  = (tid <= i) ? sc[tid] : -INFINITY;
    float mx = v;
    #pragma unroll
    for(int off=32; off; off>>=1) mx = fmaxf(mx, __shfl_xor(mx, off));
    float ex = (tid <= i) ? expf(v - mx) : 0.f;
    float sm = ex;
    #pragma unroll
    for(int off=32; off; off>>=1) sm += __shfl_xor(sm, off);
    sc[tid] = ex / sm;
  }
  __syncthreads();
  const int e4 = tid*4;
  float c0=0.f, c1=0.f, c2=0.f, c3=0.f;
  for(int L=0; L<=i; ++L){
    float wl = sc[L];
    short4 hv = *(const short4*)&histbf[((size_t)L*B_ + b)*E_ + e4];
    c0 += wl*bf2f((u16)hv.x);
    c1 += wl*bf2f((u16)hv.y);
    c2 += wl*bf2f((u16)hv.z);
    c3 += wl*bf2f((u16)hv.w);
  }
  const u16* xi = featsbf + ((size_t)b*T_ + i)*E_ + e4;
  xcbf[(size_t)b*E_ + e4 + 0] = f2bf(bf2f(xi[0]) + c0);
  xcbf[(size_t)b*E_ + e4 + 1] = f2bf(bf2f(xi[1]) + c1);
  xcbf[(size_t)b*E_ + e4 + 2] = f2bf(bf2f(xi[2]) + c2);
  xcbf[(size_t)b*E_ + e4 + 3] = f2bf(bf2f(xi[3]) + c3);
}

__device__ __forceinline__ void gru_comb(const float* __restrict__ part, int R, int J, int KS,
                                         const float* __restrict__ bih, const float* __restrict__ bhh,
                                         const float* __restrict__ hprev_f,
                                         float* __restrict__ dst_f,
                                         u16* __restrict__ dstbf,
                                         float* __restrict__ dst_seq, int idx)
{
  const int b = idx / J, e = idx - b*J;
  float ir=0.f, iz=0.f, in_=0.f, hr=0.f, hz=0.f, hn=0.f;
  for(int ks=0; ks<KS; ++ks){
    const float* p0 = part + (size_t)(ks*B_ + b)*R;
    const float* p1 = part + (size_t)((KS+ks)*B_ + b)*R;
    ir += p0[e]; iz += p0[J+e]; in_ += p0[2*J+e];
    hr += p1[e]; hz += p1[J+e]; hn  += p1[2*J+e];
  }
  ir += bih[e]; iz += bih[J+e]; in_ += bih[2*J+e];
  hr += bhh[e]; hz += bhh[J+e]; hn  += bhh[2*J+e];
  const float r = sigm(ir + hr);
  const float z = sigm(iz + hz);
  const float n = tanhf(in_ + r*hn);
  const float hp = hprev_f[(size_t)b*J + e];
  const float h2 = (1.f - z)*n + z*hp;
  dst_f[(size_t)b*J + e] = h2;
  dstbf[(size_t)b*J + e] = f2bf(h2);
  if(dst_seq) dst_seq[(size_t)b*J + e] = h2;
}

// A(i): g-gemm(i) [384] | e-gemm(i-1) [192] | att(i) [32]   grid 608
__global__ __launch_bounds__(256) void k_A(GArg2 g0, GArg2 g1, GArg2 e0, GArg2 e1,
    float* __restrict__ part_g, float* __restrict__ part_e,
    const float* __restrict__ q, const u16* __restrict__ histbf,
    const u16* __restrict__ featsbf, u16* __restrict__ xcbf, int i)
{
  __shared__ __align__(16) char smem[21504];
  const int x = blockIdx.x;
  if(x < 384){
    if(i >= T_) return;
    const int xt = x % 24, ks = (x/24) & 7, z = x/192;
    gemm32v2(z ? g1 : g0, 3*E_, xt, ks, 8, z, part_g, smem);
  } else if(x < 576){
    if(i < 1) return;
    const int ix = x-384, xt = ix % 12, ks = (ix/12) & 7, z = ix/96;
    gemm32v2(z ? e1 : e0, 3*HH_, xt, ks, 8, z, part_e, smem);
  } else {
    if(i >= T_) return;
    att_body(q, histbf, featsbf, xcbf, i, x-576, smem);
  }
}

// B(i): g-comb(i) [128] | p-gemm(i) [384] | e-comb(i-1) [64]   grid 576
__global__ __launch_bounds__(256) void k_B(GArg2 p0, GArg2 p1,
    const float* __restrict__ part_g, const float* __restrict__ part_e,
    const float* __restrict__ g_bih, const float* __restrict__ g_bhh,
    const float* __restrict__ e_bih, const float* __restrict__ e_bhh,
    const float* __restrict__ gf_prev, float* __restrict__ gf_next,
    u16* __restrict__ histbf,
    float* __restrict__ emof, u16* __restrict__ emobf,
    float* __restrict__ emo_seq, float* __restrict__ part_p, int i)
{
  __shared__ __align__(16) char smem[21504];
  const int x = blockIdx.x;
  if(x < 128){
    if(i >= T_) return;
    gru_comb(part_g, 3*E_, E_, 8, g_bih, g_bhh,
             gf_prev, gf_next, histbf + (size_t)(i+1)*B_*E_, nullptr,
             x*256 + (int)threadIdx.x);
  } else if(x < 512){
    if(i >= T_) return;
    const int ix = x-128, xt = ix % 24, ks = (ix/24) & 7, z = ix/192;
    gemm32v2(z ? p1 : p0, 3*E_, xt, ks, 8, z, part_p, smem);
  } else {
    if(i < 1) return;
    gru_comb(part_e, 3*HH_, HH_, 8, e_bih, e_bhh,
             emof, emof, emobf, emo_seq + (size_t)(i-1)*B_*HH_,
             (x-512)*256 + (int)threadIdx.x);
  }
}

// C(i): p-comb(i)   grid 128
__global__ __launch_bounds__(256) void k_C(const float* __restrict__ part_p,
    const float* __restrict__ p_bih, const float* __restrict__ p_bhh,
    float* __restrict__ partyf_p, u16* __restrict__ partybf_p)
{
  const int idx = blockIdx.x*256 + threadIdx.x;
  gru_comb(part_p, 3*E_, E_, 8, p_bih, p_bhh, partyf_p, partyf_p, partybf_p, nullptr, idx);
}

// classifier
__global__ __launch_bounds__(256) void classify(const float* __restrict__ emo_seq,
    const float* __restrict__ clsW, const float* __restrict__ clsb, float* __restrict__ out)
{
  const int idx = blockIdx.x*256 + threadIdx.x;
  if(idx >= B_*T_*C_) return;
  const int c = idx % C_;
  const int bt = idx / C_;
  const int t = bt % T_, b = bt / T_;
  const float* e = emo_seq + (size_t)(t*B_ + b)*HH_;
  const float* w = clsW + (size_t)c*HH_;
  float s = clsb[c];
  for(int h=0; h<HH_; ++h) s += e[h]*w[h];
  out[idx] = s;
}

// ===========================================================================
extern "C" void kernel_launch(void* const* d_in, const int* in_sizes, int n_in,
                              void* d_out, int out_size, void* d_ws, size_t ws_size,
                              hipStream_t stream)
{
  const float* input  = (const float*)d_in[0];
  const float* Wih_f  = (const float*)d_in[1];
  const float* Whh_f  = (const float*)d_in[2];
  const float* b_f    = (const float*)d_in[3];
  const float* Wih_b  = (const float*)d_in[4];
  const float* Whh_b  = (const float*)d_in[5];
  const float* b_b    = (const float*)d_in[6];
  const float* W_att  = (const float*)d_in[7];
  const float* g_Wih  = (const float*)d_in[8];
  const float* g_Whh  = (const float*)d_in[9];
  const float* g_bih  = (const float*)d_in[10];
  const float* g_bhh  = (const float*)d_in[11];
  const float* p_Wih  = (const float*)d_in[12];
  const float* p_Whh  = (const float*)d_in[13];
  const float* p_bih  = (const float*)d_in[14];
  const float* p_bhh  = (const float*)d_in[15];
  const float* e_Wih  = (const float*)d_in[16];
  const float* e_Whh  = (const float*)d_in[17];
  const float* e_bih  = (const float*)d_in[18];
  const float* e_bhh  = (const float*)d_in[19];
  const float* cls_W  = (const float*)d_in[20];
  const float* cls_b  = (const float*)d_in[21];

  // ---- workspace layout ----
  char* base = (char*)d_ws;
  size_t off = 0;
  auto alloc = [&](size_t bytes)->char*{
    char* p = base + off; off += (bytes + 255) & ~(size_t)255; return p;
  };
  u16*   Wpk     = (u16*)alloc((size_t)32*26*4096*2);       // 6.8 MB
  u16*   xpk     = (u16*)alloc((size_t)32*16*10*4096*2);    // 41.9 MB (phase1 only)
  u16*   hpkA    = (u16*)alloc((size_t)2*16*16*4096*2);     // 4.19 MB (phase1 only)
  u16*   hpkB    = (u16*)alloc((size_t)2*16*16*4096*2);     // 4.19 MB (phase1 only, adjacent)
  u16*   featsbf = (u16*)alloc((size_t)N_*E_*2);
  u16*   eWih    = (u16*)alloc((size_t)3*HH_*E_*2);
  u16*   eWhh    = (u16*)alloc((size_t)3*HH_*HH_*2);
  u16*   histbf  = (u16*)alloc((size_t)(T_+1)*B_*E_*2);
  float* gfbuf   = (float*)alloc((size_t)2*B_*E_*4);
  float* partyf  = (float*)alloc((size_t)2*B_*E_*4);
  u16*   partybf = (u16*)alloc((size_t)2*B_*E_*2);
  float* emof    = (float*)alloc((size_t)B_*HH_*4);
  u16*   emobf   = (u16*)alloc((size_t)B_*HH_*2);
  float* emo_seq = (float*)alloc((size_t)T_*B_*HH_*4);
  u16*   xcbf    = (u16*)alloc((size_t)B_*E_*2);
  float* part_p  = (float*)alloc((size_t)16*B_*3*E_*4);     // 6.29 MB
  u32*   bar     = (u32*)alloc(32*sizeof(u32));
  // phase-2 buffers aliased into phase-1-only regions:
  u16*   gWih    = (u16*)((char*)xpk + 0);                  // 6.29 MB
  u16*   gWhh    = (u16*)((char*)xpk + 6291456);            // 6.29 MB
  u16*   pWih    = (u16*)((char*)xpk + 12582912);           // 6.29 MB
  u16*   pWhh    = (u16*)((char*)xpk + 18874368);           // 6.29 MB
  float* part_e  = (float*)((char*)xpk + 25165824);         // 3.15 MB
  float* q       = (float*)((char*)xpk + 28311552);         // 8.39 MB
  u16*   WattT   = (u16*)((char*)xpk + 36700160);           // 2.10 MB (ends 38.8 <= 41.9)
  float* part_g  = (float*)hpkA;                            // 6.29 <= 8.39 MB (hpkA+hpkB)

  // ---- zero-init ----
  hipMemsetAsync(hpkA,    0, (size_t)2*16*16*4096*2, stream);
  hipMemsetAsync(bar,     0, 32*sizeof(u32), stream);
  hipMemsetAsync(histbf,  0, (size_t)B_*E_*2, stream);        // slice 0
  hipMemsetAsync(gfbuf,   0, (size_t)B_*E_*4, stream);        // slice 0
  hipMemsetAsync(partyf,  0, (size_t)2*B_*E_*4, stream);
  hipMemsetAsync(partybf, 0, (size_t)2*B_*E_*2, stream);
  hipMemsetAsync(emof,    0, (size_t)B_*HH_*4, stream);
  hipMemsetAsync(emobf,   0, (size_t)B_*HH_*2, stream);

  // ---- pre-pass packing (phase 1 inputs) ----
  k_pack_w<<<dim3(((size_t)32*26*4096 + 255)/256), 256, 0, stream>>>(Wih_f, Whh_f, Wih_b, Whh_b, Wpk);
  k_pack_x<<<dim3(((size_t)32*16*10*4096 + 255)/256), 256, 0, stream>>>(input, xpk);

  // ---- Phase 1: persistent BiLSTM (one launch, 32 internal steps) ----
  lstm_p<<<dim3(512), 256, 0, stream>>>(xpk, Wpk, b_f, b_b, hpkA, hpkB, featsbf, bar);

  // ---- phase-2 weight conversions (AFTER phase 1: they alias xpk) ----
  k_f2bf<<<dim3((3*E_*E_+255)/256), 256, 0, stream>>>(g_Wih, gWih, 3*E_*E_);
  k_f2bf<<<dim3((3*E_*E_+255)/256), 256, 0, stream>>>(g_Whh, gWhh, 3*E_*E_);
  k_f2bf<<<dim3((3*E_*E_+255)/256), 256, 0, stream>>>(p_Wih, pWih, 3*E_*E_);
  k_f2bf<<<dim3((3*E_*E_+255)/256), 256, 0, stream>>>(p_Whh, pWhh, 3*E_*E_);
  k_f2bf<<<dim3((3*HH_*E_+255)/256), 256, 0, stream>>>(e_Wih, eWih, 3*HH_*E_);
  k_f2bf<<<dim3((3*HH_*HH_+255)/256), 256, 0, stream>>>(e_Whh, eWhh, 3*HH_*HH_);
  k_wattT<<<dim3((E_*E_+255)/256), 256, 0, stream>>>(W_att, WattT);

  // ---- q = feats @ W_att ----
  k_qgemm<<<dim3(32, 16), 256, 0, stream>>>(featsbf, WattT, q);

  // ---- Phase 2: 3 launches/step ----
  for(int i=0; i<=T_; ++i){
    const int p  = i & 1;
    const int pe = (i-1) & 1;
    GArg2 ga0{ featsbf + (size_t)i*E_, partybf + (size_t)p*B_*E_, (long)T_*E_, (long)E_, gWih, E_ };
    GArg2 ga1{ histbf + (size_t)i*B_*E_, nullptr, (long)E_, 0, gWhh, E_ };
    GArg2 ea0{ partybf + (size_t)pe*B_*E_, nullptr, (long)E_, 0, eWih, E_ };
    GArg2 ea1{ emobf, nullptr, (long)HH_, 0, eWhh, HH_ };
    k_A<<<dim3(608), 256, 0, stream>>>(ga0, ga1, ea0, ea1, part_g, part_e,
                                       q, histbf, featsbf, xcbf, i);
    GArg2 pa0{ xcbf, nullptr, (long)E_, 0, pWih, E_ };
    GArg2 pa1{ partybf + (size_t)p*B_*E_, nullptr, (long)E_, 0, pWhh, E_ };
    k_B<<<dim3(576), 256, 0, stream>>>(pa0, pa1, part_g, part_e,
                                       g_bih, g_bhh, e_bih, e_bhh,
                                       gfbuf + (size_t)(i&1)*B_*E_,
                                       gfbuf + (size_t)((i+1)&1)*B_*E_,
                                       histbf, emof, emobf, emo_seq, part_p, i);
    if(i < T_){
      k_C<<<dim3(128), 256, 0, stream>>>(part_p, p_bih, p_bhh,
                                         partyf + (size_t)p*B_*E_,
                                         partybf + (size_t)p*B_*E_);
    }
  }

  // ---- classifier ----
  classify<<<dim3((B_*T_*C_+255)/256), 256, 0, stream>>>(emo_seq, cls_W, cls_b, (float*)d_out);
}

// Round 8
// 2618.414 us; speedup vs baseline: 1.7722x; 1.7722x over previous
//
#include <hip/hip_runtime.h>
#include <math.h>

#define B_  32
#define T_  64
#define TW_ 32
#define EW_ 300
#define H_  512
#define E_  1024
#define HH_ 512
#define C_  7
#define N_  2048   // B*T

typedef float f32x4 __attribute__((ext_vector_type(4)));
typedef short s16x8 __attribute__((ext_vector_type(8)));
typedef unsigned short u16;
typedef unsigned int u32;

__device__ __forceinline__ float sigm(float x){ return 1.f/(1.f+expf(-x)); }
__device__ __forceinline__ float bf2f(u16 u){
  union{float f; unsigned v;} x; x.v = ((unsigned)u)<<16; return x.f;
}
__device__ __forceinline__ u16 f2bf(float f){
  union{float f; unsigned v;} x; x.f = f;
  unsigned r = x.v + 0x7FFF + ((x.v>>16)&1);
  return (u16)(r>>16);
}
// async 16B global->LDS (dest: wave-uniform base + lane*16)
__device__ __forceinline__ void g2lds16(const void* g, void* l){
  __builtin_amdgcn_global_load_lds((const __attribute__((address_space(1))) u32*)g,
                                   (__attribute__((address_space(3))) u32*)l, 16, 0, 0);
}

// ===========================================================================
// Pre-pass packing kernels
// ===========================================================================
// Wpk[pan(32)][kc(26)][row(128)=g*32+ml][32], R = g*512 + mt*32 + ml
__global__ __launch_bounds__(256) void k_pack_w(
    const float* __restrict__ Wih_f, const float* __restrict__ Whh_f,
    const float* __restrict__ Wih_b, const float* __restrict__ Whh_b,
    u16* __restrict__ Wpk)
{
  size_t idx = (size_t)blockIdx.x*256 + threadIdx.x;
  if(idx >= (size_t)32*26*4096) return;
  int c   = (int)(idx & 31);
  int row = (int)((idx >> 5) & 127);
  int kc  = (int)((idx >> 12) % 26);
  int pan = (int)(idx / ((size_t)26*4096));
  int dir = pan >> 4, mt = pan & 15;
  int g = row >> 5, ml = row & 31;
  int R = g*512 + mt*32 + ml;
  int k = kc*32 + c;
  const float* Wih = dir ? Wih_b : Wih_f;
  const float* Whh = dir ? Whh_b : Whh_f;
  float v = (k < 320) ? ((k < EW_) ? Wih[(size_t)R*EW_ + k] : 0.f)
                      : Whh[(size_t)R*H_ + (k-320)];
  Wpk[idx] = f2bf(v);
}

// xpk[wt(32)][nt(32)][kc(10)][row(64)][32]; n = nt*64+row, k = kc*32+c
__global__ __launch_bounds__(256) void k_pack_x(
    const float* __restrict__ input, u16* __restrict__ xpk)
{
  size_t idx = (size_t)blockIdx.x*256 + threadIdx.x;
  if(idx >= (size_t)32*32*10*2048) return;
  int c   = (int)(idx & 31);
  int row = (int)((idx >> 5) & 63);
  int kc  = (int)((idx >> 11) % 10);
  int q2  = (int)((idx >> 11) / 10);      // wt*32+nt
  int nt  = q2 & 31, wt = q2 >> 5;
  int n = nt*64 + row;
  int k = kc*32 + c;
  float v = (k < EW_) ? input[((size_t)n*TW_ + wt)*EW_ + k] : 0.f;
  xpk[idx] = f2bf(v);
}

__global__ __launch_bounds__(256) void k_f2bf(const float* __restrict__ src,
                                              u16* __restrict__ dst, int n)
{
  int idx = blockIdx.x*256 + threadIdx.x;
  if(idx < n) dst[idx] = f2bf(src[idx]);
}

__global__ __launch_bounds__(256) void k_wattT(const float* __restrict__ W,
                                               u16* __restrict__ dst)
{
  int idx = blockIdx.x*256 + threadIdx.x;
  if(idx >= E_*E_) return;
  int j = idx >> 10, k = idx & 1023;
  dst[idx] = f2bf(W[(size_t)k*E_ + j]);   // dst[j][k] = W[k][j]
}

// ===========================================================================
// Phase 1: BiLSTM step, R8: 64n x 128gc tiles, grid (32 panels, 32 nt) = 1024
// blocks -> 4 blocks/CU (16 waves/CU) to double DMA concurrency. 3-buffer
// LDS (36KB), counted vmcnt(3), depth-2 prefetch. W-panel-per-XCD placement
// preserved (linear id%8 = panel%8).
// ===========================================================================
__global__ __launch_bounds__(256, 4) void lstm4(
    const u16* __restrict__ xpk, const u16* __restrict__ Wpk,
    const float* __restrict__ b_f, const float* __restrict__ b_b,
    const u16* __restrict__ hpk_in, u16* __restrict__ hpk_out,
    float* __restrict__ cb, u16* __restrict__ featsbf, int t)
{
  const int panel = blockIdx.x, nt = blockIdx.y;     // panel: dir=&1, mt=>>1
  const int dir = panel & 1, mt = panel >> 1;
  const int wt = dir ? (TW_-1-t) : t;
  const u16* srcW = Wpk + (size_t)(dir*16+mt)*26*4096;
  const u16* srcX = xpk + (size_t)(wt*32+nt)*10*2048;
  const u16* srcH = hpk_in + (size_t)(dir*32+nt)*16*2048;

  __shared__ __align__(16) u16 As[3][2048];   // 4KB each: 64n x 32k
  __shared__ __align__(16) u16 Bs[3][4096];   // 8KB each: 128gc x 32k

  const int tid = threadIdx.x;
  const int w = tid >> 6, l = tid & 63;
  const int lr = l & 15, lh = l >> 4;
  const int wn = w >> 1, wm = w & 1;          // wn: n-half (32 rows), wm: m-half

  f32x4 acc[2][4];
  #pragma unroll
  for(int a=0;a<2;a++)
    #pragma unroll
    for(int g=0;g<4;g++) acc[a][g] = (f32x4){0.f,0.f,0.f,0.f};

  // per chunk per wave: 1 A-load + 2 B-loads, each 1KB lane-contiguous
  auto stage = [&](int kc, int b){
    const u16* aB = (kc < 10) ? (srcX + (size_t)kc*2048) : (srcH + (size_t)(kc-10)*2048);
    const u16* bB = srcW + (size_t)kc*4096;
    g2lds16((const char*)aB + w*1024 + l*16,       (char*)&As[b][0] + w*1024);
    g2lds16((const char*)bB + (w*2)*1024 + l*16,   (char*)&Bs[b][0] + (w*2)*1024);
    g2lds16((const char*)bB + (w*2+1)*1024 + l*16, (char*)&Bs[b][0] + (w*2+1)*1024);
  };

  stage(0, 0);
  stage(1, 1);
  #pragma unroll
  for(int kc=0; kc<26; ++kc){
    // outstanding/wave at wait: chunk kc (3, oldest) + chunk kc+1 (3)
    if(kc < 25) asm volatile("s_waitcnt vmcnt(3)" ::: "memory");
    else        asm volatile("s_waitcnt vmcnt(0)" ::: "memory");
    __builtin_amdgcn_s_barrier();
    __builtin_amdgcn_sched_barrier(0);
    if(kc+2 < 26) stage(kc+2, (kc+2)%3);
    const int cu = kc % 3;
    s16x8 av[2], bv[4];
    #pragma unroll
    for(int nf=0; nf<2; ++nf)
      av[nf] = *(const s16x8*)&As[cu][(wn*32 + nf*16 + lr)*32 + lh*8];
    #pragma unroll
    for(int g=0; g<4; ++g)
      bv[g] = *(const s16x8*)&Bs[cu][(g*32 + wm*16 + lr)*32 + lh*8];
    #pragma unroll
    for(int g=0; g<4; ++g)
      #pragma unroll
      for(int nf=0; nf<2; ++nf)
        acc[nf][g] = __builtin_amdgcn_mfma_f32_16x16x32_bf16(av[nf], bv[g], acc[nf][g], 0,0,0);
  }

  // ---- cell update epilogue; h written in packed layout ----
  const float* bias = dir ? b_b : b_f;
  const int col = wm*16 + lr;                  // m-local in [0,32)
  const int m = mt*32 + col;                   // dir-local m in [0,512)
  const float bi = bias[m], bfv = bias[H_+m], bg = bias[2*H_+m], bo = bias[3*H_+m];
  float* cbp = cb + (size_t)dir*N_*H_;
  u16* hop = hpk_out + ((size_t)(dir*32+nt)*16 + mt)*2048;
  const int n0 = nt*64;
  #pragma unroll
  for(int nf=0; nf<2; ++nf){
    #pragma unroll
    for(int r=0; r<4; ++r){
      const int row = wn*32 + nf*16 + lh*4 + r;
      const int n = n0 + row;
      float gi = acc[nf][0][r] + bi;
      float gf = acc[nf][1][r] + bfv;
      float gc = acc[nf][2][r] + bg;
      float go = acc[nf][3][r] + bo;
      float c_old = cbp[(size_t)n*H_ + m];
      float c2 = sigm(gf)*c_old + sigm(gi)*tanhf(gc);
      float h2 = sigm(go)*tanhf(c2);
      cbp[(size_t)n*H_ + m] = c2;
      if(t == TW_-1) featsbf[(size_t)n*E_ + dir*H_ + m] = f2bf(h2);
      else           hop[row*32 + col] = f2bf(h2);
    }
  }
}

// ===========================================================================
// q = feats @ W_att  (one-time, bf16 MFMA, fp32 out)  [verified]
// ===========================================================================
__global__ __launch_bounds__(256) void k_qgemm(const u16* __restrict__ featsbf,
                                               const u16* __restrict__ WattT,
                                               float* __restrict__ q)
{
  const int n0 = blockIdx.x*64, j0 = blockIdx.y*64;
  __shared__ __align__(16) u16 As[64*40];
  __shared__ __align__(16) u16 Bs[64*40];
  const int tid = threadIdx.x;
  const int w = tid>>6, l = tid&63, lr = l&15, lk = (l>>4)*8;
  const int arow = tid>>2, ak8 = (tid&3)*8;

  f32x4 acc[4];
  #pragma unroll
  for(int i=0;i<4;i++) acc[i] = (f32x4){0.f,0.f,0.f,0.f};

  for(int kc=0; kc<32; ++kc){
    *(s16x8*)&As[arow*40 + ak8] = *(const s16x8*)&featsbf[(size_t)(n0+arow)*E_ + kc*32 + ak8];
    *(s16x8*)&Bs[arow*40 + ak8] = *(const s16x8*)&WattT[(size_t)(j0+arow)*E_ + kc*32 + ak8];
    __syncthreads();
    s16x8 av = *(const s16x8*)&As[(w*16 + lr)*40 + lk];
    #pragma unroll
    for(int mf=0; mf<4; ++mf){
      s16x8 bv = *(const s16x8*)&Bs[(mf*16 + lr)*40 + lk];
      acc[mf] = __builtin_amdgcn_mfma_f32_16x16x32_bf16(av, bv, acc[mf], 0,0,0);
    }
    __syncthreads();
  }
  #pragma unroll
  for(int mf=0; mf<4; ++mf)
    #pragma unroll
    for(int r=0; r<4; ++r){
      int n = n0 + w*16 + (l>>4)*4 + r;
      q[(size_t)n*E_ + j0 + mf*16 + lr] = acc[mf][r];
    }
}

// ===========================================================================
// Phase 2 building blocks  [unchanged - verified correct R4-R7]
// ===========================================================================
struct GArg2 {
  const u16* xA; const u16* xB;
  long ldA; long ldB;
  const u16* W; int K;
};

__device__ __forceinline__ void gemm32v2(const GArg2 a, int R, int xt, int ks,
                                         int KS, int z, float* __restrict__ part,
                                         char* smem)
{
  u16* Xs0 = (u16*)smem;
  u16* Xs1 = Xs0 + 32*40;
  u16* Ws0 = Xs1 + 32*40;
  u16* Ws1 = Ws0 + 128*32;
  const int Kc = a.K / KS;
  const int nch = Kc >> 5;
  const int kb0 = ks * Kc;
  const int tid = threadIdx.x;
  const int w = tid>>6, l = tid&63, lr = l&15, lh = l>>4;

  f32x4 a00={0,0,0,0}, a01={0,0,0,0}, a10={0,0,0,0}, a11={0,0,0,0};

  auto issueW = [&](int c, u16* Wb){
    const int kb = kb0 + c*32;
    #pragma unroll
    for(int c2=0;c2<2;++c2){
      const int cc = w*2 + c2;
      const char* g = (const char*)(a.W + (size_t)(xt*128 + cc*16 + (l>>2))*a.K + kb) + (l&3)*16;
      g2lds16(g, (char*)Wb + cc*1024);
    }
  };
  auto loadX = [&](int c, short4* xr){
    const int kb = kb0 + c*32;
    const int row = tid>>3, k4 = (tid&7)*4;
    short4 xv = *(const short4*)&a.xA[(size_t)row*a.ldA + kb + k4];
    if(a.xB){
      short4 yv = *(const short4*)&a.xB[(size_t)row*a.ldB + kb + k4];
      xv.x = (short)f2bf(bf2f((u16)xv.x)+bf2f((u16)yv.x));
      xv.y = (short)f2bf(bf2f((u16)xv.y)+bf2f((u16)yv.y));
      xv.z = (short)f2bf(bf2f((u16)xv.z)+bf2f((u16)yv.z));
      xv.w = (short)f2bf(bf2f((u16)xv.w)+bf2f((u16)yv.w));
    }
    *xr = xv;
  };
  auto writeX = [&](short4 xv, u16* Xb){
    *(short4*)&Xb[(tid>>3)*40 + (tid&7)*4] = xv;
  };

  short4 xr;
  issueW(0, Ws0); loadX(0, &xr); writeX(xr, Xs0);
  __syncthreads();
  for(int c=0;c<nch;++c){
    u16* Xc = (c&1)?Xs1:Xs0; u16* Wc = (c&1)?Ws1:Ws0;
    u16* Xn = (c&1)?Xs0:Xs1; u16* Wn = (c&1)?Ws0:Ws1;
    const bool pre = (c+1 < nch);
    if(pre){ issueW(c+1, Wn); loadX(c+1, &xr); }
    s16x8 av0 = *(const s16x8*)&Xc[lr*40 + lh*8];
    s16x8 av1 = *(const s16x8*)&Xc[(16+lr)*40 + lh*8];
    s16x8 bv0 = *(const s16x8*)&Wc[(w*32 + lr)*32 + lh*8];
    s16x8 bv1 = *(const s16x8*)&Wc[(w*32 + 16 + lr)*32 + lh*8];
    a00 = __builtin_amdgcn_mfma_f32_16x16x32_bf16(av0, bv0, a00, 0,0,0);
    a01 = __builtin_amdgcn_mfma_f32_16x16x32_bf16(av0, bv1, a01, 0,0,0);
    a10 = __builtin_amdgcn_mfma_f32_16x16x32_bf16(av1, bv0, a10, 0,0,0);
    a11 = __builtin_amdgcn_mfma_f32_16x16x32_bf16(av1, bv1, a11, 0,0,0);
    if(pre) writeX(xr, Xn);
    __syncthreads();
  }
  float* dst = part + (size_t)((z*KS + ks)*B_)*R + xt*128 + w*32;
  f32x4 accs[2][2] = {{a00,a01},{a10,a11}};
  #pragma unroll
  for(int nf=0; nf<2; ++nf)
    #pragma unroll
    for(int mf=0; mf<2; ++mf)
      #pragma unroll
      for(int r=0; r<4; ++r){
        int n = nf*16 + lh*4 + r;
        dst[(size_t)n*R + mf*16 + lr] = accs[nf][mf][r];
      }
}

__device__ __forceinline__ void att_body(const float* __restrict__ q,
                                         const u16* __restrict__ histbf,
                                         const u16* __restrict__ featsbf,
                                         u16* __restrict__ xcbf,
                                         int i, int b, char* smem)
{
  float* qs = (float*)smem;      // 1024
  float* sc = qs + E_;           // 64
  const int tid = threadIdx.x;
  *(float4*)&qs[tid*4] = *(const float4*)&q[((size_t)b*T_ + i)*E_ + tid*4];
  __syncthreads();
  const int wv = tid>>6, ln = tid&63;
  for(int L = wv; L <= i; L += 4){
    const u16* hl = histbf + ((size_t)L*B_ + b)*E_;
    float s = 0.f;
    s16x8 h0 = *(const s16x8*)&hl[ln*16];
    s16x8 h1 = *(const s16x8*)&hl[ln*16 + 8];
    #pragma unroll
    for(int j=0;j<8;j++){
      s += qs[ln*16 + j]     * bf2f((u16)h0[j]);
      s += qs[ln*16 + 8 + j] * bf2f((u16)h1[j]);
    }
    #pragma unroll
    for(int off=32; off; off>>=1) s += __shfl_down(s, off);
    if(ln == 0) sc[L] = s;
  }
  __syncthreads();
  if(tid < 64){
    float v  = (tid <= i) ? sc[tid] : -INFINITY;
    float mx = v;
    #pragma unroll
    for(int off=32; off; off>>=1) mx = fmaxf(mx, __shfl_xor(mx, off));
    float ex = (tid <= i) ? expf(v - mx) : 0.f;
    float sm = ex;
    #pragma unroll
    for(int off=32; off; off>>=1) sm += __shfl_xor(sm, off);
    sc[tid] = ex / sm;
  }
  __syncthreads();
  const int e4 = tid*4;
  float c0=0.f, c1=0.f, c2=0.f, c3=0.f;
  for(int L=0; L<=i; ++L){
    float wl = sc[L];
    short4 hv = *(const short4*)&histbf[((size_t)L*B_ + b)*E_ + e4];
    c0 += wl*bf2f((u16)hv.x);
    c1 += wl*bf2f((u16)hv.y);
    c2 += wl*bf2f((u16)hv.z);
    c3 += wl*bf2f((u16)hv.w);
  }
  const u16* xi = featsbf + ((size_t)b*T_ + i)*E_ + e4;
  xcbf[(size_t)b*E_ + e4 + 0] = f2bf(bf2f(xi[0]) + c0);
  xcbf[(size_t)b*E_ + e4 + 1] = f2bf(bf2f(xi[1]) + c1);
  xcbf[(size_t)b*E_ + e4 + 2] = f2bf(bf2f(xi[2]) + c2);
  xcbf[(size_t)b*E_ + e4 + 3] = f2bf(bf2f(xi[3]) + c3);
}

__device__ __forceinline__ void gru_comb(const float* __restrict__ part, int R, int J, int KS,
                                         const float* __restrict__ bih, const float* __restrict__ bhh,
                                         const float* __restrict__ hprev_f,
                                         float* __restrict__ dst_f,
                                         u16* __restrict__ dstbf,
                                         float* __restrict__ dst_seq, int idx)
{
  const int b = idx / J, e = idx - b*J;
  float ir=0.f, iz=0.f, in_=0.f, hr=0.f, hz=0.f, hn=0.f;
  for(int ks=0; ks<KS; ++ks){
    const float* p0 = part + (size_t)(ks*B_ + b)*R;
    const float* p1 = part + (size_t)((KS+ks)*B_ + b)*R;
    ir += p0[e]; iz += p0[J+e]; in_ += p0[2*J+e];
    hr += p1[e]; hz += p1[J+e]; hn  += p1[2*J+e];
  }
  ir += bih[e]; iz += bih[J+e]; in_ += bih[2*J+e];
  hr += bhh[e]; hz += bhh[J+e]; hn  += bhh[2*J+e];
  const float r = sigm(ir + hr);
  const float z = sigm(iz + hz);
  const float n = tanhf(in_ + r*hn);
  const float hp = hprev_f[(size_t)b*J + e];
  const float h2 = (1.f - z)*n + z*hp;
  dst_f[(size_t)b*J + e] = h2;
  dstbf[(size_t)b*J + e] = f2bf(h2);
  if(dst_seq) dst_seq[(size_t)b*J + e] = h2;
}

// A(i): g-gemm(i) [384] | e-gemm(i-1) [192] | att(i) [32]   grid 608
__global__ __launch_bounds__(256) void k_A(GArg2 g0, GArg2 g1, GArg2 e0, GArg2 e1,
    float* __restrict__ part_g, float* __restrict__ part_e,
    const float* __restrict__ q, const u16* __restrict__ histbf,
    const u16* __restrict__ featsbf, u16* __restrict__ xcbf, int i)
{
  __shared__ __align__(16) char smem[21504];
  const int x = blockIdx.x;
  if(x < 384){
    if(i >= T_) return;
    const int xt = x % 24, ks = (x/24) & 7, z = x/192;
    gemm32v2(z ? g1 : g0, 3*E_, xt, ks, 8, z, part_g, smem);
  } else if(x < 576){
    if(i < 1) return;
    const int ix = x-384, xt = ix % 12, ks = (ix/12) & 7, z = ix/96;
    gemm32v2(z ? e1 : e0, 3*HH_, xt, ks, 8, z, part_e, smem);
  } else {
    if(i >= T_) return;
    att_body(q, histbf, featsbf, xcbf, i, x-576, smem);
  }
}

// B(i): g-comb(i) [128] | p-gemm(i) [384] | e-comb(i-1) [64]   grid 576
__global__ __launch_bounds__(256) void k_B(GArg2 p0, GArg2 p1,
    const float* __restrict__ part_g, const float* __restrict__ part_e,
    const float* __restrict__ g_bih, const float* __restrict__ g_bhh,
    const float* __restrict__ e_bih, const float* __restrict__ e_bhh,
    const float* __restrict__ gf_prev, float* __restrict__ gf_next,
    u16* __restrict__ histbf,
    float* __restrict__ emof, u16* __restrict__ emobf,
    float* __restrict__ emo_seq, float* __restrict__ part_p, int i)
{
  __shared__ __align__(16) char smem[21504];
  const int x = blockIdx.x;
  if(x < 128){
    if(i >= T_) return;
    gru_comb(part_g, 3*E_, E_, 8, g_bih, g_bhh,
             gf_prev, gf_next, histbf + (size_t)(i+1)*B_*E_, nullptr,
             x*256 + (int)threadIdx.x);
  } else if(x < 512){
    if(i >= T_) return;
    const int ix = x-128, xt = ix % 24, ks = (ix/24) & 7, z = ix/192;
    gemm32v2(z ? p1 : p0, 3*E_, xt, ks, 8, z, part_p, smem);
  } else {
    if(i < 1) return;
    gru_comb(part_e, 3*HH_, HH_, 8, e_bih, e_bhh,
             emof, emof, emobf, emo_seq + (size_t)(i-1)*B_*HH_,
             (x-512)*256 + (int)threadIdx.x);
  }
}

// C(i): p-comb(i)   grid 128
__global__ __launch_bounds__(256) void k_C(const float* __restrict__ part_p,
    const float* __restrict__ p_bih, const float* __restrict__ p_bhh,
    float* __restrict__ partyf_p, u16* __restrict__ partybf_p)
{
  const int idx = blockIdx.x*256 + threadIdx.x;
  gru_comb(part_p, 3*E_, E_, 8, p_bih, p_bhh, partyf_p, partyf_p, partybf_p, nullptr, idx);
}

// classifier
__global__ __launch_bounds__(256) void classify(const float* __restrict__ emo_seq,
    const float* __restrict__ clsW, const float* __restrict__ clsb, float* __restrict__ out)
{
  const int idx = blockIdx.x*256 + threadIdx.x;
  if(idx >= B_*T_*C_) return;
  const int c = idx % C_;
  const int bt = idx / C_;
  const int t = bt % T_, b = bt / T_;
  const float* e = emo_seq + (size_t)(t*B_ + b)*HH_;
  const float* w = clsW + (size_t)c*HH_;
  float s = clsb[c];
  for(int h=0; h<HH_; ++h) s += e[h]*w[h];
  out[idx] = s;
}

// ===========================================================================
extern "C" void kernel_launch(void* const* d_in, const int* in_sizes, int n_in,
                              void* d_out, int out_size, void* d_ws, size_t ws_size,
                              hipStream_t stream)
{
  const float* input  = (const float*)d_in[0];
  const float* Wih_f  = (const float*)d_in[1];
  const float* Whh_f  = (const float*)d_in[2];
  const float* b_f    = (const float*)d_in[3];
  const float* Wih_b  = (const float*)d_in[4];
  const float* Whh_b  = (const float*)d_in[5];
  const float* b_b    = (const float*)d_in[6];
  const float* W_att  = (const float*)d_in[7];
  const float* g_Wih  = (const float*)d_in[8];
  const float* g_Whh  = (const float*)d_in[9];
  const float* g_bih  = (const float*)d_in[10];
  const float* g_bhh  = (const float*)d_in[11];
  const float* p_Wih  = (const float*)d_in[12];
  const float* p_Whh  = (const float*)d_in[13];
  const float* p_bih  = (const float*)d_in[14];
  const float* p_bhh  = (const float*)d_in[15];
  const float* e_Wih  = (const float*)d_in[16];
  const float* e_Whh  = (const float*)d_in[17];
  const float* e_bih  = (const float*)d_in[18];
  const float* e_bhh  = (const float*)d_in[19];
  const float* cls_W  = (const float*)d_in[20];
  const float* cls_b  = (const float*)d_in[21];

  // ---- workspace layout ----
  char* base = (char*)d_ws;
  size_t off = 0;
  auto alloc = [&](size_t bytes)->char*{
    char* p = base + off; off += (bytes + 255) & ~(size_t)255; return p;
  };
  u16*   Wpk     = (u16*)alloc((size_t)32*26*4096*2);       // 6.8 MB
  u16*   xpk     = (u16*)alloc((size_t)32*32*10*2048*2);    // 41.9 MB (phase1 only)
  u16*   hpkA    = (u16*)alloc((size_t)2*32*16*2048*2);     // 4.19 MB (phase1 only)
  u16*   hpkB    = (u16*)alloc((size_t)2*32*16*2048*2);     // 4.19 MB (phase1 only, adjacent)
  float* cb      = (float*)alloc((size_t)2*N_*H_*4);        // 8.39 MB (phase1 only)
  u16*   featsbf = (u16*)alloc((size_t)N_*E_*2);
  u16*   eWih    = (u16*)alloc((size_t)3*HH_*E_*2);
  u16*   eWhh    = (u16*)alloc((size_t)3*HH_*HH_*2);
  u16*   histbf  = (u16*)alloc((size_t)(T_+1)*B_*E_*2);
  float* gfbuf   = (float*)alloc((size_t)2*B_*E_*4);
  float* partyf  = (float*)alloc((size_t)2*B_*E_*4);
  u16*   partybf = (u16*)alloc((size_t)2*B_*E_*2);
  float* emof    = (float*)alloc((size_t)B_*HH_*4);
  u16*   emobf   = (u16*)alloc((size_t)B_*HH_*2);
  float* emo_seq = (float*)alloc((size_t)T_*B_*HH_*4);
  u16*   xcbf    = (u16*)alloc((size_t)B_*E_*2);
  float* part_p  = (float*)alloc((size_t)16*B_*3*E_*4);     // 6.29 MB
  // phase-2 buffers aliased into phase-1-only regions:
  u16*   gWih    = (u16*)((char*)xpk + 0);                  // 6.29 MB
  u16*   gWhh    = (u16*)((char*)xpk + 6291456);            // 6.29 MB
  u16*   pWih    = (u16*)((char*)xpk + 12582912);           // 6.29 MB
  u16*   pWhh    = (u16*)((char*)xpk + 18874368);           // 6.29 MB
  float* part_e  = (float*)((char*)xpk + 25165824);         // 3.15 MB
  float* q       = (float*)((char*)xpk + 28311552);         // 8.39 MB
  u16*   WattT   = (u16*)((char*)xpk + 36700160);           // 2.10 MB (ends 38.8 <= 41.9)
  float* part_g  = (float*)hpkA;                            // 6.29 <= 8.39 MB (hpkA+hpkB)

  // ---- zero-init ----
  hipMemsetAsync(hpkA,    0, (size_t)2*32*16*2048*2, stream);
  hipMemsetAsync(cb,      0, (size_t)2*N_*H_*4, stream);
  hipMemsetAsync(histbf,  0, (size_t)B_*E_*2, stream);        // slice 0
  hipMemsetAsync(gfbuf,   0, (size_t)B_*E_*4, stream);        // slice 0
  hipMemsetAsync(partyf,  0, (size_t)2*B_*E_*4, stream);
  hipMemsetAsync(partybf, 0, (size_t)2*B_*E_*2, stream);
  hipMemsetAsync(emof,    0, (size_t)B_*HH_*4, stream);
  hipMemsetAsync(emobf,   0, (size_t)B_*HH_*2, stream);

  // ---- pre-pass packing (phase 1 inputs) ----
  k_pack_w<<<dim3(((size_t)32*26*4096 + 255)/256), 256, 0, stream>>>(Wih_f, Whh_f, Wih_b, Whh_b, Wpk);
  k_pack_x<<<dim3(((size_t)32*32*10*2048 + 255)/256), 256, 0, stream>>>(input, xpk);

  // ---- Phase 1: BiLSTM, 1024 blocks (4/CU) per step ----
  for(int t=0; t<TW_; ++t){
    u16* hin  = (t & 1) ? hpkB : hpkA;
    u16* hout = (t & 1) ? hpkA : hpkB;
    lstm4<<<dim3(32, 32), 256, 0, stream>>>(xpk, Wpk, b_f, b_b, hin, hout, cb, featsbf, t);
  }

  // ---- phase-2 weight conversions (AFTER phase 1: they alias xpk) ----
  k_f2bf<<<dim3((3*E_*E_+255)/256), 256, 0, stream>>>(g_Wih, gWih, 3*E_*E_);
  k_f2bf<<<dim3((3*E_*E_+255)/256), 256, 0, stream>>>(g_Whh, gWhh, 3*E_*E_);
  k_f2bf<<<dim3((3*E_*E_+255)/256), 256, 0, stream>>>(p_Wih, pWih, 3*E_*E_);
  k_f2bf<<<dim3((3*E_*E_+255)/256), 256, 0, stream>>>(p_Whh, pWhh, 3*E_*E_);
  k_f2bf<<<dim3((3*HH_*E_+255)/256), 256, 0, stream>>>(e_Wih, eWih, 3*HH_*E_);
  k_f2bf<<<dim3((3*HH_*HH_+255)/256), 256, 0, stream>>>(e_Whh, eWhh, 3*HH_*HH_);
  k_wattT<<<dim3((E_*E_+255)/256), 256, 0, stream>>>(W_att, WattT);

  // ---- q = feats @ W_att ----
  k_qgemm<<<dim3(32, 16), 256, 0, stream>>>(featsbf, WattT, q);

  // ---- Phase 2: 3 launches/step ----
  for(int i=0; i<=T_; ++i){
    const int p  = i & 1;
    const int pe = (i-1) & 1;
    GArg2 ga0{ featsbf + (size_t)i*E_, partybf + (size_t)p*B_*E_, (long)T_*E_, (long)E_, gWih, E_ };
    GArg2 ga1{ histbf + (size_t)i*B_*E_, nullptr, (long)E_, 0, gWhh, E_ };
    GArg2 ea0{ partybf + (size_t)pe*B_*E_, nullptr, (long)E_, 0, eWih, E_ };
    GArg2 ea1{ emobf, nullptr, (long)HH_, 0, eWhh, HH_ };
    k_A<<<dim3(608), 256, 0, stream>>>(ga0, ga1, ea0, ea1, part_g, part_e,
                                       q, histbf, featsbf, xcbf, i);
    GArg2 pa0{ xcbf, nullptr, (long)E_, 0, pWih, E_ };
    GArg2 pa1{ partybf + (size_t)p*B_*E_, nullptr, (long)E_, 0, pWhh, E_ };
    k_B<<<dim3(576), 256, 0, stream>>>(pa0, pa1, part_g, part_e,
                                       g_bih, g_bhh, e_bih, e_bhh,
                                       gfbuf + (size_t)(i&1)*B_*E_,
                                       gfbuf + (size_t)((i+1)&1)*B_*E_,
                                       histbf, emof, emobf, emo_seq, part_p, i);
    if(i < T_){
      k_C<<<dim3(128), 256, 0, stream>>>(part_p, p_bih, p_bhh,
                                         partyf + (size_t)p*B_*E_,
                                         partybf + (size_t)p*B_*E_);
    }
  }

  // ---- classifier ----
  classify<<<dim3((B_*T_*C_+255)/256), 256, 0, stream>>>(emo_seq, cls_W, cls_b, (float*)d_out);
}